// Round 4
// baseline (145.270 us; speedup 1.0000x reference)
//
#include <hip/hip_runtime.h>
#include <hip/hip_fp16.h>

#define N_POINTS   100000
#define N_EVENTS   1000000
#define N_PAIRS    100000
#define N_RIEMANN  128
#define EPS_F      1e-6f
#define NON_EVENT_W 1.0f

constexpr int BLOCK       = 256;

// ---- event side: 8 contiguous events per thread (16 gathers in flight) ----
constexpr int EVPT        = 8;
constexpr int EV_THREADS  = N_EVENTS / EVPT;                    // 125000 (exact)
constexpr int EV_BLOCKS   = (EV_THREADS + BLOCK - 1) / BLOCK;   // 489

// ---- pair side: each pair split across 4 threads, 32 Riemann steps each ----
constexpr int RPT          = 32;                                // Riemann steps per thread
constexpr int CHUNKS       = N_RIEMANN / RPT;                   // 4
constexpr int PAIR_THREADS = N_PAIRS * CHUNKS;                  // 400000
constexpr int PAIR_BLOCKS  = (PAIR_THREADS + BLOCK - 1) / BLOCK; // 1563

constexpr int MAIN_BLOCKS = PAIR_BLOCKS + EV_BLOCKS;            // 2052; pairs FIRST (R1 winner)
constexpr int PREP_BLOCKS = (N_POINTS + BLOCK - 1) / BLOCK;

// Packed point record (16 B): half2 z | half2 v | half2 a | pad.
// One dwordx4 gather per point; 4 points per 64 B line; table = 1.6 MB (L2-resident).

__device__ __forceinline__ float block_reduce_sum(float v) {
    #pragma unroll
    for (int off = 32; off > 0; off >>= 1)
        v += __shfl_down(v, off, 64);
    __shared__ float smem[BLOCK / 64];
    const int lane = threadIdx.x & 63;
    const int wid  = threadIdx.x >> 6;
    if (lane == 0) smem[wid] = v;
    __syncthreads();
    float r = 0.f;
    if (threadIdx.x == 0) {
        #pragma unroll
        for (int i = 0; i < BLOCK / 64; ++i) r += smem[i];
    }
    return r;
}

__device__ __forceinline__ void decode_rec(const float4& r, float2& z, float2& v, float2& a) {
    z = __half22float2(*reinterpret_cast<const __half2*>(&r.x));
    v = __half22float2(*reinterpret_cast<const __half2*>(&r.y));
    a = __half22float2(*reinterpret_cast<const __half2*>(&r.z));
}

__global__ __launch_bounds__(BLOCK) void prep_kernel(
    const float2* __restrict__ z0,
    const float2* __restrict__ v0,
    const float2* __restrict__ a0,
    float4*       __restrict__ pts,
    unsigned int* __restrict__ ticket)
{
    const int i = blockIdx.x * BLOCK + threadIdx.x;
    if (i == 0) *ticket = 0u;                       // reset last-block-done counter each launch
    if (i < N_POINTS) {
        const float2 z = z0[i], v = v0[i], a = a0[i];
        float4 r;
        *reinterpret_cast<__half2*>(&r.x) = __float22half2_rn(make_float2(z.x, z.y));
        *reinterpret_cast<__half2*>(&r.y) = __float22half2_rn(make_float2(v.x, v.y));
        *reinterpret_cast<__half2*>(&r.z) = __float22half2_rn(make_float2(a.x, a.y));
        r.w = 0.f;
        pts[i] = r;
    }
}

template <bool PACKED>
__global__ __launch_bounds__(BLOCK) void main_kernel(
    const float4* __restrict__ pts,
    const float2* __restrict__ z0,
    const float2* __restrict__ v0,
    const float2* __restrict__ a0,
    const float*  __restrict__ beta,
    const int*    __restrict__ eu,
    const int*    __restrict__ ev,
    const float*  __restrict__ et,
    const int*    __restrict__ pu,
    const int*    __restrict__ pv,
    const float*  __restrict__ t0p,
    const float*  __restrict__ tnp,
    float*        __restrict__ partials,
    unsigned int* __restrict__ ticket,
    float*        __restrict__ out)
{
    float acc = 0.f;
    const int b = blockIdx.x;

    if (b < PAIR_BLOCKS) {
        // ---- non-event term: 4 threads per pair, 32 Riemann steps each (long loop FIRST) ----
        const int p = b * BLOCK + threadIdx.x;
        if (p < PAIR_THREADS) {
            const int chunk = p / N_PAIRS;               // 0..3 (magic-mul, once)
            const int pr    = p - chunk * N_PAIRS;
            const float t0v  = t0p[0];
            const float tnv  = tnp[0];
            const float step = (tnv - t0v) * (1.0f / N_RIEMANN);   // == dt
            const float bb   = beta[0];
            const int iu = pu[pr];
            const int iv = pv[pr];
            float dzx, dzy, dvx, dvy, dax, day;
            if constexpr (PACKED) {
                const float4 ru = pts[iu];
                const float4 rv = pts[iv];
                float2 zu, vu, au, zv, vv, av;
                decode_rec(ru, zu, vu, au);
                decode_rec(rv, zv, vv, av);
                dzx = zu.x - zv.x; dzy = zu.y - zv.y;
                dvx = vu.x - vv.x; dvy = vu.y - vv.y;
                dax = au.x - av.x; day = au.y - av.y;
            } else {
                const float2 zu = z0[iu], zv = z0[iv];
                const float2 vu = v0[iu], vv = v0[iv];
                const float2 au = a0[iu], av = a0[iv];
                dzx = zu.x - zv.x; dzy = zu.y - zv.y;
                dvx = vu.x - vv.x; dvy = vu.y - vv.y;
                dax = au.x - av.x; day = au.y - av.y;
            }
            // fold EPS into dz, 0.5 into da: per-step body is 2 fma per dim
            const float dzxe = dzx + EPS_F;
            const float dzye = dzy + EPS_F;
            const float hax  = 0.5f * dax;
            const float hay  = 0.5f * day;
            float s = 0.f;
            const int k0 = chunk * RPT;
            #pragma unroll 8
            for (int k = k0; k < k0 + RPT; ++k) {
                const float t  = __fmaf_rn((float)k, step, t0v);
                const float h  = t * t;                    // 0.5 folded into hax/hay
                const float dx = __fmaf_rn(hax, h, __fmaf_rn(dvx, t, dzxe));
                const float dy = __fmaf_rn(hay, h, __fmaf_rn(dvy, t, dzye));
                const float d  = __builtin_amdgcn_sqrtf(__fmaf_rn(dy, dy, dx * dx));
                s += __expf(-d);
            }
            acc = -NON_EVENT_W * step * __expf(bb) * s;
        }
    } else {
        // ---- event term: 8 contiguous events/thread; vectorized streams + 16 gathers in flight ----
        const int t = (b - PAIR_BLOCKS) * BLOCK + threadIdx.x;
        if (t < EV_THREADS) {
            const int4*   eu4 = reinterpret_cast<const int4*>(eu);
            const int4*   ev4 = reinterpret_cast<const int4*>(ev);
            const float4* et4 = reinterpret_cast<const float4*>(et);
            const int4 u0 = eu4[2 * t], u1 = eu4[2 * t + 1];
            const int4 w0 = ev4[2 * t], w1 = ev4[2 * t + 1];
            const float4 t0q = et4[2 * t], t1q = et4[2 * t + 1];
            const int iu[EVPT] = { u0.x, u0.y, u0.z, u0.w, u1.x, u1.y, u1.z, u1.w };
            const int iv[EVPT] = { w0.x, w0.y, w0.z, w0.w, w1.x, w1.y, w1.z, w1.w };
            const float te[EVPT] = { t0q.x, t0q.y, t0q.z, t0q.w, t1q.x, t1q.y, t1q.z, t1q.w };
            if constexpr (PACKED) {
                float4 ru[EVPT], rv[EVPT];
                #pragma unroll
                for (int j = 0; j < EVPT; ++j) ru[j] = pts[iu[j]];
                #pragma unroll
                for (int j = 0; j < EVPT; ++j) rv[j] = pts[iv[j]];
                #pragma unroll
                for (int j = 0; j < EVPT; ++j) {
                    float2 zu, vu, au, zv, vv, av;
                    decode_rec(ru[j], zu, vu, au);
                    decode_rec(rv[j], zv, vv, av);
                    const float h = 0.5f * te[j] * te[j];
                    const float dx = (zu.x - zv.x) + (vu.x - vv.x) * te[j] + (au.x - av.x) * h + EPS_F;
                    const float dy = (zu.y - zv.y) + (vu.y - vv.y) * te[j] + (au.y - av.y) * h + EPS_F;
                    acc -= __builtin_amdgcn_sqrtf(__fmaf_rn(dy, dy, dx * dx));
                }
            } else {
                #pragma unroll
                for (int j = 0; j < EVPT; ++j) {
                    const float2 zu = z0[iu[j]], zv = z0[iv[j]];
                    const float2 vu = v0[iu[j]], vv = v0[iv[j]];
                    const float2 au = a0[iu[j]], av = a0[iv[j]];
                    const float h = 0.5f * te[j] * te[j];
                    const float dx = (zu.x - zv.x) + (vu.x - vv.x) * te[j] + (au.x - av.x) * h + EPS_F;
                    const float dy = (zu.y - zv.y) + (vu.y - vv.y) * te[j] + (au.y - av.y) * h + EPS_F;
                    acc -= __builtin_amdgcn_sqrtf(__fmaf_rn(dy, dy, dx * dx));
                }
            }
        }
    }

    const float r = block_reduce_sum(acc);

    if (ticket != nullptr) {
        // ---- last-block-done reduction: kills the reduce dispatch; summation order is
        //      IDENTICAL to the old reduce_kernel (deterministic, absmax-stable).
        __shared__ bool amLast;
        if (threadIdx.x == 0) {
            partials[blockIdx.x] = r;
            __threadfence();                              // release: partial visible device-wide
            const unsigned prev = atomicAdd(ticket, 1u);  // device-scope by default
            amLast = (prev == (unsigned)(MAIN_BLOCKS - 1));
        }
        __syncthreads();
        if (amLast) {
            __threadfence();                              // acquire: no stale partials via L1
            float a2 = 0.f;
            for (int i = threadIdx.x; i < MAIN_BLOCKS; i += BLOCK) a2 += partials[i];
            const float rr = block_reduce_sum(a2);
            if (threadIdx.x == 0) out[0] = beta[0] * (float)N_EVENTS + rr;
        }
    } else {
        if (threadIdx.x == 0) partials[blockIdx.x] = r;   // fallback: separate reduce dispatch
    }
}

__global__ __launch_bounds__(BLOCK) void reduce_kernel(        // fallback path only
    const float* __restrict__ partials,
    const float* __restrict__ beta,
    float*       __restrict__ out)
{
    float acc = 0.f;
    for (int i = threadIdx.x; i < MAIN_BLOCKS; i += BLOCK) acc += partials[i];
    const float r = block_reduce_sum(acc);
    if (threadIdx.x == 0) out[0] = beta[0] * (float)N_EVENTS + r;
}

extern "C" void kernel_launch(void* const* d_in, const int* in_sizes, int n_in,
                              void* d_out, int out_size, void* d_ws, size_t ws_size,
                              hipStream_t stream) {
    const float*  beta = (const float*)d_in[0];
    const float2* z0   = (const float2*)d_in[1];
    const float2* v0   = (const float2*)d_in[2];
    const float2* a0   = (const float2*)d_in[3];
    const int*    eu   = (const int*)d_in[4];
    const int*    ev   = (const int*)d_in[5];
    const float*  et   = (const float*)d_in[6];
    const int*    pu   = (const int*)d_in[7];
    const int*    pv   = (const int*)d_in[8];
    const float*  t0p  = (const float*)d_in[9];
    const float*  tnp  = (const float*)d_in[10];

    float* out = (float*)d_out;
    const size_t pts_bytes  = (size_t)N_POINTS * sizeof(float4);
    const size_t part_bytes = (size_t)MAIN_BLOCKS * sizeof(float);
    const bool packed = (ws_size >= pts_bytes + part_bytes + sizeof(unsigned int));

    if (packed) {
        float4*       pts      = (float4*)d_ws;
        float*        partials = (float*)((char*)d_ws + pts_bytes);
        unsigned int* ticket   = (unsigned int*)((char*)d_ws + pts_bytes + part_bytes);
        prep_kernel<<<PREP_BLOCKS, BLOCK, 0, stream>>>(z0, v0, a0, pts, ticket);
        main_kernel<true><<<MAIN_BLOCKS, BLOCK, 0, stream>>>(
            pts, z0, v0, a0, beta, eu, ev, et, pu, pv, t0p, tnp, partials, ticket, out);
        // no reduce dispatch: last main block folds partials deterministically
    } else {
        float* partials = (float*)d_ws;       // fallback: fp32 path, 2 dispatches
        main_kernel<false><<<MAIN_BLOCKS, BLOCK, 0, stream>>>(
            nullptr, z0, v0, a0, beta, eu, ev, et, pu, pv, t0p, tnp, partials, nullptr, out);
        reduce_kernel<<<1, BLOCK, 0, stream>>>(partials, beta, out);
    }
}

// Round 5
// 100.804 us; speedup vs baseline: 1.4411x; 1.4411x over previous
//
#include <hip/hip_runtime.h>
#include <hip/hip_fp16.h>

#define N_POINTS   100000
#define N_EVENTS   1000000
#define N_PAIRS    100000
#define N_RIEMANN  128
#define EPS_F      1e-6f
#define NON_EVENT_W 1.0f

constexpr int BLOCK       = 256;

// ---- event side: 8 contiguous events per thread (16 gathers in flight) ----
constexpr int EVPT        = 8;
constexpr int EV_THREADS  = N_EVENTS / EVPT;                    // 125000 (exact)
constexpr int EV_BLOCKS   = (EV_THREADS + BLOCK - 1) / BLOCK;   // 489

// ---- pair side: 4 chunk-threads per pair, ADJACENT LANES of one wave ----
// pair = q>>2, chunk = q&3  ->  the 4 lanes gather the SAME two pts records:
// the TA coalesces same-line lanes, cutting pair-side L2 requests 4x vs the
// old chunk-major mapping (chunks of one pair used to sit in different blocks).
constexpr int RPT          = 32;                                // Riemann steps per thread
constexpr int CHUNKS       = N_RIEMANN / RPT;                   // 4
constexpr int PAIR_THREADS = N_PAIRS * CHUNKS;                  // 400000
constexpr int PAIR_BLOCKS  = (PAIR_THREADS + BLOCK - 1) / BLOCK; // 1563

constexpr int MAIN_BLOCKS = PAIR_BLOCKS + EV_BLOCKS;            // 2052; pairs FIRST (R1 winner)
constexpr int PREP_BLOCKS = (N_POINTS + BLOCK - 1) / BLOCK;

// Packed point record (16 B): half2 z | half2 v | half2 a | pad.
// One dwordx4 gather per point; 4 points per 64 B line; table = 1.6 MB (L2-resident).
// NOTE (R4 lesson): no device-scope fences / tickets anywhere — on gfx950 the
// non-coherent per-XCD L2s make __threadfence() ~ a full L2 writeback (+30 us).

__device__ __forceinline__ float block_reduce_sum(float v) {
    #pragma unroll
    for (int off = 32; off > 0; off >>= 1)
        v += __shfl_down(v, off, 64);
    __shared__ float smem[BLOCK / 64];
    const int lane = threadIdx.x & 63;
    const int wid  = threadIdx.x >> 6;
    if (lane == 0) smem[wid] = v;
    __syncthreads();
    float r = 0.f;
    if (threadIdx.x == 0) {
        #pragma unroll
        for (int i = 0; i < BLOCK / 64; ++i) r += smem[i];
    }
    return r;
}

__device__ __forceinline__ void decode_rec(const float4& r, float2& z, float2& v, float2& a) {
    z = __half22float2(*reinterpret_cast<const __half2*>(&r.x));
    v = __half22float2(*reinterpret_cast<const __half2*>(&r.y));
    a = __half22float2(*reinterpret_cast<const __half2*>(&r.z));
}

__global__ __launch_bounds__(BLOCK) void prep_kernel(
    const float2* __restrict__ z0,
    const float2* __restrict__ v0,
    const float2* __restrict__ a0,
    float4*       __restrict__ pts)
{
    const int i = blockIdx.x * BLOCK + threadIdx.x;
    if (i < N_POINTS) {
        const float2 z = z0[i], v = v0[i], a = a0[i];
        float4 r;
        *reinterpret_cast<__half2*>(&r.x) = __float22half2_rn(make_float2(z.x, z.y));
        *reinterpret_cast<__half2*>(&r.y) = __float22half2_rn(make_float2(v.x, v.y));
        *reinterpret_cast<__half2*>(&r.z) = __float22half2_rn(make_float2(a.x, a.y));
        r.w = 0.f;
        pts[i] = r;
    }
}

// __launch_bounds__(256, 4): cap 128 VGPR/wave (vs 40 before) so the event
// path can hold all 16 float4 gather results in flight (R4 showed VGPR=40 ->
// MLP collapsed to ~4). 4 blocks/CU min is still ample TLP for both phases.
template <bool PACKED>
__global__ __launch_bounds__(BLOCK, 4) void main_kernel(
    const float4* __restrict__ pts,
    const float2* __restrict__ z0,
    const float2* __restrict__ v0,
    const float2* __restrict__ a0,
    const float*  __restrict__ beta,
    const int*    __restrict__ eu,
    const int*    __restrict__ ev,
    const float*  __restrict__ et,
    const int*    __restrict__ pu,
    const int*    __restrict__ pv,
    const float*  __restrict__ t0p,
    const float*  __restrict__ tnp,
    float*        __restrict__ partials)
{
    float acc = 0.f;
    const int b = blockIdx.x;

    if (b < PAIR_BLOCKS) {
        // ---- non-event term: 4 adjacent lanes per pair, 32 Riemann steps each ----
        const int q = b * BLOCK + threadIdx.x;
        if (q < PAIR_THREADS) {
            const int pr    = q >> 2;                    // pair index (shared by 4 lanes)
            const int chunk = q & 3;                     // Riemann chunk 0..3
            const float t0v  = t0p[0];
            const float tnv  = tnp[0];
            const float step = (tnv - t0v) * (1.0f / N_RIEMANN);   // == dt
            const float bb   = beta[0];
            const int iu = pu[pr];                       // 4 lanes same addr -> 1 request
            const int iv = pv[pr];
            float dzx, dzy, dvx, dvy, dax, day;
            if constexpr (PACKED) {
                const float4 ru = pts[iu];               // 4 lanes same 16B line -> coalesced
                const float4 rv = pts[iv];
                float2 zu, vu, au, zv, vv, av;
                decode_rec(ru, zu, vu, au);
                decode_rec(rv, zv, vv, av);
                dzx = zu.x - zv.x; dzy = zu.y - zv.y;
                dvx = vu.x - vv.x; dvy = vu.y - vv.y;
                dax = au.x - av.x; day = au.y - av.y;
            } else {
                const float2 zu = z0[iu], zv = z0[iv];
                const float2 vu = v0[iu], vv = v0[iv];
                const float2 au = a0[iu], av = a0[iv];
                dzx = zu.x - zv.x; dzy = zu.y - zv.y;
                dvx = vu.x - vv.x; dvy = vu.y - vv.y;
                dax = au.x - av.x; day = au.y - av.y;
            }
            // fold EPS into dz, 0.5 into da: per-step body is 2 fma per dim
            const float dzxe = dzx + EPS_F;
            const float dzye = dzy + EPS_F;
            const float hax  = 0.5f * dax;
            const float hay  = 0.5f * day;
            float s = 0.f;
            const int k0 = chunk * RPT;
            #pragma unroll 8
            for (int k = k0; k < k0 + RPT; ++k) {
                const float t  = __fmaf_rn((float)k, step, t0v);
                const float h  = t * t;                    // 0.5 folded into hax/hay
                const float dx = __fmaf_rn(hax, h, __fmaf_rn(dvx, t, dzxe));
                const float dy = __fmaf_rn(hay, h, __fmaf_rn(dvy, t, dzye));
                const float d  = __builtin_amdgcn_sqrtf(__fmaf_rn(dy, dy, dx * dx));
                s += __expf(-d);
            }
            acc = -NON_EVENT_W * step * __expf(bb) * s;
        }
    } else {
        // ---- event term: 8 contiguous events/thread; vectorized streams + 16 gathers in flight ----
        const int t = (b - PAIR_BLOCKS) * BLOCK + threadIdx.x;
        if (t < EV_THREADS) {
            const int4*   eu4 = reinterpret_cast<const int4*>(eu);
            const int4*   ev4 = reinterpret_cast<const int4*>(ev);
            const float4* et4 = reinterpret_cast<const float4*>(et);
            const int4 u0 = eu4[2 * t], u1 = eu4[2 * t + 1];
            const int4 w0 = ev4[2 * t], w1 = ev4[2 * t + 1];
            const float4 t0q = et4[2 * t], t1q = et4[2 * t + 1];
            const int iu[EVPT] = { u0.x, u0.y, u0.z, u0.w, u1.x, u1.y, u1.z, u1.w };
            const int iv[EVPT] = { w0.x, w0.y, w0.z, w0.w, w1.x, w1.y, w1.z, w1.w };
            const float te[EVPT] = { t0q.x, t0q.y, t0q.z, t0q.w, t1q.x, t1q.y, t1q.z, t1q.w };
            if constexpr (PACKED) {
                float4 ru[EVPT], rv[EVPT];
                #pragma unroll
                for (int j = 0; j < EVPT; ++j) ru[j] = pts[iu[j]];
                #pragma unroll
                for (int j = 0; j < EVPT; ++j) rv[j] = pts[iv[j]];
                #pragma unroll
                for (int j = 0; j < EVPT; ++j) {
                    float2 zu, vu, au, zv, vv, av;
                    decode_rec(ru[j], zu, vu, au);
                    decode_rec(rv[j], zv, vv, av);
                    const float h = 0.5f * te[j] * te[j];
                    const float dx = (zu.x - zv.x) + (vu.x - vv.x) * te[j] + (au.x - av.x) * h + EPS_F;
                    const float dy = (zu.y - zv.y) + (vu.y - vv.y) * te[j] + (au.y - av.y) * h + EPS_F;
                    acc -= __builtin_amdgcn_sqrtf(__fmaf_rn(dy, dy, dx * dx));
                }
            } else {
                #pragma unroll
                for (int j = 0; j < EVPT; ++j) {
                    const float2 zu = z0[iu[j]], zv = z0[iv[j]];
                    const float2 vu = v0[iu[j]], vv = v0[iv[j]];
                    const float2 au = a0[iu[j]], av = a0[iv[j]];
                    const float h = 0.5f * te[j] * te[j];
                    const float dx = (zu.x - zv.x) + (vu.x - vv.x) * te[j] + (au.x - av.x) * h + EPS_F;
                    const float dy = (zu.y - zv.y) + (vu.y - vv.y) * te[j] + (au.y - av.y) * h + EPS_F;
                    acc -= __builtin_amdgcn_sqrtf(__fmaf_rn(dy, dy, dx * dx));
                }
            }
        }
    }

    const float r = block_reduce_sum(acc);
    if (threadIdx.x == 0) partials[blockIdx.x] = r;   // no atomics, no fences
}

__global__ __launch_bounds__(BLOCK) void reduce_kernel(
    const float* __restrict__ partials,
    const float* __restrict__ beta,
    float*       __restrict__ out)
{
    float acc = 0.f;
    for (int i = threadIdx.x; i < MAIN_BLOCKS; i += BLOCK) acc += partials[i];
    const float r = block_reduce_sum(acc);
    if (threadIdx.x == 0) out[0] = beta[0] * (float)N_EVENTS + r;
}

extern "C" void kernel_launch(void* const* d_in, const int* in_sizes, int n_in,
                              void* d_out, int out_size, void* d_ws, size_t ws_size,
                              hipStream_t stream) {
    const float*  beta = (const float*)d_in[0];
    const float2* z0   = (const float2*)d_in[1];
    const float2* v0   = (const float2*)d_in[2];
    const float2* a0   = (const float2*)d_in[3];
    const int*    eu   = (const int*)d_in[4];
    const int*    ev   = (const int*)d_in[5];
    const float*  et   = (const float*)d_in[6];
    const int*    pu   = (const int*)d_in[7];
    const int*    pv   = (const int*)d_in[8];
    const float*  t0p  = (const float*)d_in[9];
    const float*  tnp  = (const float*)d_in[10];

    float* out = (float*)d_out;
    const size_t pts_bytes = (size_t)N_POINTS * sizeof(float4);
    const bool packed = (ws_size >= pts_bytes + (size_t)MAIN_BLOCKS * sizeof(float));

    if (packed) {
        float4* pts      = (float4*)d_ws;
        float*  partials = (float*)((char*)d_ws + pts_bytes);
        prep_kernel<<<PREP_BLOCKS, BLOCK, 0, stream>>>(z0, v0, a0, pts);
        main_kernel<true><<<MAIN_BLOCKS, BLOCK, 0, stream>>>(
            pts, z0, v0, a0, beta, eu, ev, et, pu, pv, t0p, tnp, partials);
        reduce_kernel<<<1, BLOCK, 0, stream>>>(partials, beta, out);
    } else {
        float* partials = (float*)d_ws;       // needs only 8.2 KB
        main_kernel<false><<<MAIN_BLOCKS, BLOCK, 0, stream>>>(
            nullptr, z0, v0, a0, beta, eu, ev, et, pu, pv, t0p, tnp, partials);
        reduce_kernel<<<1, BLOCK, 0, stream>>>(partials, beta, out);
    }
}